// Round 1
// baseline (1500.053 us; speedup 1.0000x reference)
//
#include <hip/hip_runtime.h>

#define B_ 8
#define K_ 4096
#define C_ 128
#define KN 16

// ---------------------------------------------------------------------------
// Kernel 1: LayerNorm(x)*gamma+beta + pos_embed -> xp  [32768, 128]
// one wave per row, lane handles channels (lane, lane+64)
// ---------------------------------------------------------------------------
__global__ __launch_bounds__(256) void k_lnpos(
    const float* __restrict__ x, const float* __restrict__ pos,
    const float* __restrict__ gamma, const float* __restrict__ beta,
    float* __restrict__ xp) {
  int wave = threadIdx.x >> 6;
  int lane = threadIdx.x & 63;
  size_t row = (size_t)blockIdx.x * 4 + wave;
  const float* xr = x + row * C_;
  const float* pr = pos + row * C_;
  float a = xr[lane], b = xr[lane + 64];
  float s = a + b;
#pragma unroll
  for (int o = 1; o < 64; o <<= 1) s += __shfl_xor(s, o);
  float mu = s * (1.0f / 128.0f);
  float da = a - mu, db = b - mu;
  float v = da * da + db * db;
#pragma unroll
  for (int o = 1; o < 64; o <<= 1) v += __shfl_xor(v, o);
  float rstd = rsqrtf(v * (1.0f / 128.0f) + 1e-5f);
  float xn0 = da * rstd * gamma[lane] + beta[lane];
  float xn1 = db * rstd * gamma[lane + 64] + beta[lane + 64];
  xp[row * C_ + lane] = xn0 + pr[lane];
  xp[row * C_ + lane + 64] = xn1 + pr[lane + 64];
}

// ---------------------------------------------------------------------------
// Kernel 2: build Wcat [128, 512]
// cols 0:128   = W_a1[0:128]              (S_a)
// cols 128:256 = W_f1[0:128]-W_f1[128:256](S_f)
// cols 256:384 = W_a1[128:256]            (N_a)
// cols 384:512 = W_f1[128:256]            (N_f)
// ---------------------------------------------------------------------------
__global__ void k_wcat(const float* __restrict__ Wa1,
                       const float* __restrict__ Wf1,
                       float* __restrict__ Wcat) {
  int i = blockIdx.x * blockDim.x + threadIdx.x;  // 0..65535
  int r = i >> 9;
  int q = i & 511;
  float v;
  if (q < 128)
    v = Wa1[r * 128 + q];
  else if (q < 256)
    v = Wf1[r * 128 + (q - 128)] - Wf1[(128 + r) * 128 + (q - 128)];
  else if (q < 384)
    v = Wa1[(128 + r) * 128 + (q - 256)];
  else
    v = Wf1[(128 + r) * 128 + (q - 384)];
  Wcat[i] = v;
}

// ---------------------------------------------------------------------------
// Kernel 3: exact kNN (top-16 smallest dists, self excluded, low-index ties)
// 1 thread per query; per-batch coords+norms staged in LDS (64KB)
// distance arithmetic matches reference bit pattern: (xx_i+xx_j) + (-2*dot)
// ---------------------------------------------------------------------------
__global__ __launch_bounds__(256) void k_knn(const float* __restrict__ coords,
                                             int* __restrict__ idx) {
  __shared__ float4 cc[K_];  // x,y,z,xx
  int b = blockIdx.x >> 4;           // 16 blocks per batch
  int qbase = (blockIdx.x & 15) * 256;
  const float* cb = coords + (size_t)b * K_ * 3;
  for (int p = threadIdx.x; p < K_; p += 256) {
    float px = cb[p * 3], py = cb[p * 3 + 1], pz = cb[p * 3 + 2];
    float w = __fadd_rn(__fadd_rn(__fmul_rn(px, px), __fmul_rn(py, py)),
                        __fmul_rn(pz, pz));
    cc[p] = make_float4(px, py, pz, w);
  }
  __syncthreads();
  int qi = qbase + threadIdx.x;
  float4 q = cc[qi];
  float dk[KN];
  int ik[KN];
#pragma unroll
  for (int p = 0; p < KN; ++p) {
    dk[p] = 1e30f;
    ik[p] = 0;
  }
  for (int j = 0; j < K_; ++j) {
    float4 c = cc[j];
    float dot = __fadd_rn(__fadd_rn(__fmul_rn(q.x, c.x), __fmul_rn(q.y, c.y)),
                          __fmul_rn(q.z, c.z));
    float d = __fadd_rn(__fadd_rn(q.w, c.w), __fmul_rn(-2.0f, dot));
    if (d < dk[KN - 1] && j != qi) {
      float cd = d;
      int ci = j;
#pragma unroll
      for (int p = 0; p < KN; ++p) {
        bool lt = cd < dk[p];
        float td = dk[p];
        int ti = ik[p];
        dk[p] = lt ? cd : td;
        ik[p] = lt ? ci : ti;
        cd = lt ? td : cd;
        ci = lt ? ti : ci;
      }
    }
  }
  int* op = idx + ((size_t)b * K_ + qi) * KN;
#pragma unroll
  for (int p = 0; p < KN; ++p) op[p] = ik[p];
}

// ---------------------------------------------------------------------------
// Kernel 4: fp32 GEMM  SN[32768,512] = xp[32768,128] @ Wcat[128,512]
// 64x64 tile, full K=128, 256 threads, 4x4 microtile
// ---------------------------------------------------------------------------
__global__ __launch_bounds__(256) void k_gemm(const float* __restrict__ A,
                                              const float* __restrict__ Bw,
                                              float* __restrict__ Cm) {
  __shared__ float lA[128][64];  // [k][m]
  __shared__ float lB[128][64];  // [k][n]
  int tn = blockIdx.x & 7;
  int tmb = blockIdx.x >> 3;
  int m0 = tmb * 64;
  int n0 = tn * 64;
  int t = threadIdx.x;

  {  // stage A (transposed)
    int tr = t >> 2, tq = t & 3;
    const float* ap = A + (size_t)(m0 + tr) * 128;
#pragma unroll
    for (int u = 0; u < 8; ++u) {
      int c4 = (tq * 8 + u) * 4;
      float4 av = *(const float4*)(ap + c4);
      lA[c4 + 0][tr] = av.x;
      lA[c4 + 1][tr] = av.y;
      lA[c4 + 2][tr] = av.z;
      lA[c4 + 3][tr] = av.w;
    }
  }
  {  // stage B
    int tr = t >> 1, tq = t & 1;
    const float* bp = Bw + (size_t)tr * 512 + n0;
#pragma unroll
    for (int u = 0; u < 8; ++u) {
      int c4 = (tq * 8 + u) * 4;
      float4 bv = *(const float4*)(bp + c4);
      *(float4*)&lB[tr][c4] = bv;
    }
  }
  __syncthreads();

  int ty = t >> 4, tx = t & 15;
  int mb = ty * 4, nb = tx * 4;
  float acc[4][4];
#pragma unroll
  for (int i = 0; i < 4; ++i)
#pragma unroll
    for (int j = 0; j < 4; ++j) acc[i][j] = 0.0f;

#pragma unroll 4
  for (int k = 0; k < 128; ++k) {
    float4 av = *(float4*)&lA[k][mb];
    float4 bv = *(float4*)&lB[k][nb];
    float a4[4] = {av.x, av.y, av.z, av.w};
    float b4[4] = {bv.x, bv.y, bv.z, bv.w};
#pragma unroll
    for (int i = 0; i < 4; ++i)
#pragma unroll
      for (int j = 0; j < 4; ++j) acc[i][j] += a4[i] * b4[j];
  }

#pragma unroll
  for (int i = 0; i < 4; ++i) {
    size_t row = (size_t)(m0 + mb + i);
    float4 r = make_float4(acc[i][0], acc[i][1], acc[i][2], acc[i][3]);
    *(float4*)(Cm + row * 512 + n0 + nb) = r;
  }
}

// ---------------------------------------------------------------------------
// Kernel 5: attention aggregate. One wave per point.
// SN cols: [0:128]=S_a, [128:256]=S_f, [256:384]=N_a, [384:512]=N_f
// ---------------------------------------------------------------------------
__global__ __launch_bounds__(256) void k_attn(
    const float* __restrict__ SN, const int* __restrict__ idx,
    const float* __restrict__ b_a1, const float* __restrict__ b_f1,
    const float* __restrict__ W_a2, const float* __restrict__ b_a2,
    float* __restrict__ out) {
  int wave = threadIdx.x >> 6, lane = threadIdx.x & 63;
  size_t g = (size_t)blockIdx.x * 4 + wave;
  int b = (int)(g >> 12);
  const float* sr = SN + g * 512;
  float s_a0 = sr[lane], s_a1 = sr[lane + 64];
  float s_f0 = sr[128 + lane], s_f1 = sr[128 + lane + 64];
  float ba0 = b_a1[lane], ba1 = b_a1[lane + 64];
  float bf0 = b_f1[lane], bf1 = b_f1[lane + 64];
  float w20 = W_a2[lane], w21 = W_a2[lane + 64];
  float ba2 = b_a2[0];
  const int* ip = idx + g * 16;
  float lg[16], t0a[16], t1a[16];
#pragma unroll
  for (int j = 0; j < 16; ++j) {
    int n = ip[j];
    const float* nr = SN + ((size_t)((b << 12) + n)) * 512 + 256;
    float na0 = nr[lane], na1 = nr[lane + 64];
    float nf0 = nr[128 + lane], nf1 = nr[128 + lane + 64];
    float h0 = s_a0 + na0 + ba0;
    h0 = h0 >= 0.0f ? h0 : 0.2f * h0;
    float h1 = s_a1 + na1 + ba1;
    h1 = h1 >= 0.0f ? h1 : 0.2f * h1;
    float t0 = s_f0 + nf0 + bf0;
    t0 = t0 >= 0.0f ? t0 : 0.2f * t0;
    float t1 = s_f1 + nf1 + bf1;
    t1 = t1 >= 0.0f ? t1 : 0.2f * t1;
    float pl = h0 * w20 + h1 * w21;
#pragma unroll
    for (int o = 1; o < 64; o <<= 1) pl += __shfl_xor(pl, o);
    lg[j] = pl + ba2;
    t0a[j] = t0;
    t1a[j] = t1;
  }
  float m = lg[0];
#pragma unroll
  for (int j = 1; j < 16; ++j) m = fmaxf(m, lg[j]);
  float s = 0.0f;
  float e[16];
#pragma unroll
  for (int j = 0; j < 16; ++j) {
    e[j] = expf(lg[j] - m);
    s += e[j];
  }
  float inv = 1.0f / s;
  float o0 = 0.0f, o1 = 0.0f;
#pragma unroll
  for (int j = 0; j < 16; ++j) {
    float a = e[j] * inv;
    o0 += a * t0a[j];
    o1 += a * t1a[j];
  }
  out[g * 128 + lane] = o0;
  out[g * 128 + lane + 64] = o1;
}

// ---------------------------------------------------------------------------
extern "C" void kernel_launch(void* const* d_in, const int* in_sizes, int n_in,
                              void* d_out, int out_size, void* d_ws,
                              size_t ws_size, hipStream_t stream) {
  const float* x = (const float*)d_in[0];
  const float* pos = (const float*)d_in[1];
  const float* coords = (const float*)d_in[2];
  const float* gamma = (const float*)d_in[3];
  const float* beta = (const float*)d_in[4];
  const float* Wa1 = (const float*)d_in[5];
  const float* ba1 = (const float*)d_in[6];
  const float* Wa2 = (const float*)d_in[7];
  const float* ba2 = (const float*)d_in[8];
  const float* Wf1 = (const float*)d_in[9];
  const float* bf1 = (const float*)d_in[10];
  float* out = (float*)d_out;

  char* ws = (char*)d_ws;
  float* xp = (float*)ws;                                    // 16 MB
  float* SN = (float*)(ws + (size_t)16 * 1024 * 1024);       // 64 MB
  float* Wcat = (float*)(ws + (size_t)80 * 1024 * 1024);     // 256 KB
  int* idx = (int*)(ws + (size_t)80 * 1024 * 1024 + 512 * 1024);  // 2 MB

  k_lnpos<<<8192, 256, 0, stream>>>(x, pos, gamma, beta, xp);
  k_wcat<<<256, 256, 0, stream>>>(Wa1, Wf1, Wcat);
  k_knn<<<128, 256, 0, stream>>>(coords, idx);
  k_gemm<<<4096, 256, 0, stream>>>(xp, Wcat, SN);
  k_attn<<<8192, 256, 0, stream>>>(SN, idx, ba1, bf1, Wa2, ba2, out);
}

// Round 2
// 541.540 us; speedup vs baseline: 2.7700x; 2.7700x over previous
//
#include <hip/hip_runtime.h>

#define B_ 8
#define K_ 4096
#define C_ 128
#define KN 16
#define NPART 8
#define PCAND (K_ / NPART)  // 512

// ---------------------------------------------------------------------------
// Kernel 1: LayerNorm(x)*gamma+beta + pos_embed -> xp  [32768, 128]
// ---------------------------------------------------------------------------
__global__ __launch_bounds__(256) void k_lnpos(
    const float* __restrict__ x, const float* __restrict__ pos,
    const float* __restrict__ gamma, const float* __restrict__ beta,
    float* __restrict__ xp) {
  int wave = threadIdx.x >> 6;
  int lane = threadIdx.x & 63;
  size_t row = (size_t)blockIdx.x * 4 + wave;
  const float* xr = x + row * C_;
  const float* pr = pos + row * C_;
  float a = xr[lane], b = xr[lane + 64];
  float s = a + b;
#pragma unroll
  for (int o = 1; o < 64; o <<= 1) s += __shfl_xor(s, o);
  float mu = s * (1.0f / 128.0f);
  float da = a - mu, db = b - mu;
  float v = da * da + db * db;
#pragma unroll
  for (int o = 1; o < 64; o <<= 1) v += __shfl_xor(v, o);
  float rstd = rsqrtf(v * (1.0f / 128.0f) + 1e-5f);
  float xn0 = da * rstd * gamma[lane] + beta[lane];
  float xn1 = db * rstd * gamma[lane + 64] + beta[lane + 64];
  xp[row * C_ + lane] = xn0 + pr[lane];
  xp[row * C_ + lane + 64] = xn1 + pr[lane + 64];
}

// ---------------------------------------------------------------------------
// Kernel 2: build Wcat [128, 512]
// ---------------------------------------------------------------------------
__global__ void k_wcat(const float* __restrict__ Wa1,
                       const float* __restrict__ Wf1,
                       float* __restrict__ Wcat) {
  int i = blockIdx.x * blockDim.x + threadIdx.x;  // 0..65535
  int r = i >> 9;
  int q = i & 511;
  float v;
  if (q < 128)
    v = Wa1[r * 128 + q];
  else if (q < 256)
    v = Wf1[r * 128 + (q - 128)] - Wf1[(128 + r) * 128 + (q - 128)];
  else if (q < 384)
    v = Wa1[(128 + r) * 128 + (q - 256)];
  else
    v = Wf1[(128 + r) * 128 + (q - 384)];
  Wcat[i] = v;
}

// ---------------------------------------------------------------------------
// Kernel 3a: partial exact kNN — each block scans one 512-candidate part
// for 256 queries; per-thread sorted top-16 (strict <, ties keep lower index)
// ---------------------------------------------------------------------------
__global__ __launch_bounds__(256) void k_knn_part(
    const float* __restrict__ coords, float* __restrict__ pd,
    int* __restrict__ pi) {
  __shared__ float4 cc[PCAND];  // x,y,z,xx (8KB)
  int p = blockIdx.x & (NPART - 1);
  int qc = (blockIdx.x >> 3) & 15;
  int b = blockIdx.x >> 7;
  const float* cb = coords + (size_t)b * K_ * 3;
  int cbase = p * PCAND;
  for (int t = threadIdx.x; t < PCAND; t += 256) {
    int j = cbase + t;
    float px = cb[j * 3], py = cb[j * 3 + 1], pz = cb[j * 3 + 2];
    float w = __fadd_rn(__fadd_rn(__fmul_rn(px, px), __fmul_rn(py, py)),
                        __fmul_rn(pz, pz));
    cc[t] = make_float4(px, py, pz, w);
  }
  __syncthreads();
  int qi = qc * 256 + threadIdx.x;
  float qx = cb[qi * 3], qy = cb[qi * 3 + 1], qz = cb[qi * 3 + 2];
  float qw = __fadd_rn(__fadd_rn(__fmul_rn(qx, qx), __fmul_rn(qy, qy)),
                       __fmul_rn(qz, qz));
  float dk[KN];
  int ik[KN];
#pragma unroll
  for (int s = 0; s < KN; ++s) {
    dk[s] = 1e30f;
    ik[s] = 0;
  }
  for (int t = 0; t < PCAND; ++t) {
    float4 c = cc[t];
    float dot = __fadd_rn(__fadd_rn(__fmul_rn(qx, c.x), __fmul_rn(qy, c.y)),
                          __fmul_rn(qz, c.z));
    float d = __fadd_rn(__fadd_rn(qw, c.w), __fmul_rn(-2.0f, dot));
    int j = cbase + t;
    if (d < dk[KN - 1] && j != qi) {
      float cd = d;
      int ci = j;
#pragma unroll
      for (int s = 0; s < KN; ++s) {
        bool lt = cd < dk[s];
        float td = dk[s];
        int ti = ik[s];
        dk[s] = lt ? cd : td;
        ik[s] = lt ? ci : ti;
        cd = lt ? td : cd;
        ci = lt ? ti : ci;
      }
    }
  }
  size_t g = (size_t)b * K_ + qi;
  float* od = pd + (g * NPART + p) * KN;
  int* oi = pi + (g * NPART + p) * KN;
#pragma unroll
  for (int s = 0; s < KN; ++s) {
    od[s] = dk[s];
    oi[s] = ik[s];
  }
}

// ---------------------------------------------------------------------------
// Kernel 3b: merge 8 partial sorted lists -> final 16 indices (set semantics)
// stream order for equal distances == index order, so strict < keeps the
// same set as lax.top_k
// ---------------------------------------------------------------------------
__global__ __launch_bounds__(256) void k_knn_merge(const float* __restrict__ pd,
                                                   const int* __restrict__ pi,
                                                   int* __restrict__ idx) {
  size_t g = (size_t)blockIdx.x * 256 + threadIdx.x;  // 0..32767
  const float* dq = pd + g * (NPART * KN);
  const int* iq = pi + g * (NPART * KN);
  float dk[KN];
  int ik[KN];
#pragma unroll
  for (int s = 0; s < KN; ++s) {
    dk[s] = 1e30f;
    ik[s] = 0;
  }
  for (int t = 0; t < NPART * KN; ++t) {
    float cd = dq[t];
    int ci = iq[t];
    if (cd < dk[KN - 1]) {
#pragma unroll
      for (int s = 0; s < KN; ++s) {
        bool lt = cd < dk[s];
        float td = dk[s];
        int ti = ik[s];
        dk[s] = lt ? cd : td;
        ik[s] = lt ? ci : ti;
        cd = lt ? td : cd;
        ci = lt ? ti : ci;
      }
    }
  }
  int* op = idx + g * KN;
#pragma unroll
  for (int s = 0; s < KN; ++s) op[s] = ik[s];
}

// ---------------------------------------------------------------------------
// Kernel 4: fp32 GEMM  SN[32768,512] = xp[32768,128] @ Wcat[128,512]
// ---------------------------------------------------------------------------
__global__ __launch_bounds__(256) void k_gemm(const float* __restrict__ A,
                                              const float* __restrict__ Bw,
                                              float* __restrict__ Cm) {
  __shared__ float lA[128][64];  // [k][m]
  __shared__ float lB[128][64];  // [k][n]
  int tn = blockIdx.x & 7;
  int tmb = blockIdx.x >> 3;
  int m0 = tmb * 64;
  int n0 = tn * 64;
  int t = threadIdx.x;

  {  // stage A (transposed)
    int tr = t >> 2, tq = t & 3;
    const float* ap = A + (size_t)(m0 + tr) * 128;
#pragma unroll
    for (int u = 0; u < 8; ++u) {
      int c4 = (tq * 8 + u) * 4;
      float4 av = *(const float4*)(ap + c4);
      lA[c4 + 0][tr] = av.x;
      lA[c4 + 1][tr] = av.y;
      lA[c4 + 2][tr] = av.z;
      lA[c4 + 3][tr] = av.w;
    }
  }
  {  // stage B
    int tr = t >> 1, tq = t & 1;
    const float* bp = Bw + (size_t)tr * 512 + n0;
#pragma unroll
    for (int u = 0; u < 8; ++u) {
      int c4 = (tq * 8 + u) * 4;
      float4 bv = *(const float4*)(bp + c4);
      *(float4*)&lB[tr][c4] = bv;
    }
  }
  __syncthreads();

  int ty = t >> 4, tx = t & 15;
  int mb = ty * 4, nb = tx * 4;
  float acc[4][4];
#pragma unroll
  for (int i = 0; i < 4; ++i)
#pragma unroll
    for (int j = 0; j < 4; ++j) acc[i][j] = 0.0f;

#pragma unroll 4
  for (int k = 0; k < 128; ++k) {
    float4 av = *(float4*)&lA[k][mb];
    float4 bv = *(float4*)&lB[k][nb];
    float a4[4] = {av.x, av.y, av.z, av.w};
    float b4[4] = {bv.x, bv.y, bv.z, bv.w};
#pragma unroll
    for (int i = 0; i < 4; ++i)
#pragma unroll
      for (int j = 0; j < 4; ++j) acc[i][j] += a4[i] * b4[j];
  }

#pragma unroll
  for (int i = 0; i < 4; ++i) {
    size_t row = (size_t)(m0 + mb + i);
    float4 r = make_float4(acc[i][0], acc[i][1], acc[i][2], acc[i][3]);
    *(float4*)(Cm + row * 512 + n0 + nb) = r;
  }
}

// ---------------------------------------------------------------------------
// Kernel 5: attention aggregate. One wave per point.
// SN cols: [0:128]=S_a, [128:256]=S_f, [256:384]=N_a, [384:512]=N_f
// ---------------------------------------------------------------------------
__global__ __launch_bounds__(256) void k_attn(
    const float* __restrict__ SN, const int* __restrict__ idx,
    const float* __restrict__ b_a1, const float* __restrict__ b_f1,
    const float* __restrict__ W_a2, const float* __restrict__ b_a2,
    float* __restrict__ out) {
  int wave = threadIdx.x >> 6, lane = threadIdx.x & 63;
  size_t g = (size_t)blockIdx.x * 4 + wave;
  int b = (int)(g >> 12);
  const float* sr = SN + g * 512;
  float s_a0 = sr[lane], s_a1 = sr[lane + 64];
  float s_f0 = sr[128 + lane], s_f1 = sr[128 + lane + 64];
  float ba0 = b_a1[lane], ba1 = b_a1[lane + 64];
  float bf0 = b_f1[lane], bf1 = b_f1[lane + 64];
  float w20 = W_a2[lane], w21 = W_a2[lane + 64];
  float ba2 = b_a2[0];
  const int* ip = idx + g * 16;
  float lg[16], t0a[16], t1a[16];
#pragma unroll
  for (int j = 0; j < 16; ++j) {
    int n = ip[j];
    const float* nr = SN + ((size_t)((b << 12) + n)) * 512 + 256;
    float na0 = nr[lane], na1 = nr[lane + 64];
    float nf0 = nr[128 + lane], nf1 = nr[128 + lane + 64];
    float h0 = s_a0 + na0 + ba0;
    h0 = h0 >= 0.0f ? h0 : 0.2f * h0;
    float h1 = s_a1 + na1 + ba1;
    h1 = h1 >= 0.0f ? h1 : 0.2f * h1;
    float t0 = s_f0 + nf0 + bf0;
    t0 = t0 >= 0.0f ? t0 : 0.2f * t0;
    float t1 = s_f1 + nf1 + bf1;
    t1 = t1 >= 0.0f ? t1 : 0.2f * t1;
    float pl = h0 * w20 + h1 * w21;
#pragma unroll
    for (int o = 1; o < 64; o <<= 1) pl += __shfl_xor(pl, o);
    lg[j] = pl + ba2;
    t0a[j] = t0;
    t1a[j] = t1;
  }
  float m = lg[0];
#pragma unroll
  for (int j = 1; j < 16; ++j) m = fmaxf(m, lg[j]);
  float s = 0.0f;
  float e[16];
#pragma unroll
  for (int j = 0; j < 16; ++j) {
    e[j] = expf(lg[j] - m);
    s += e[j];
  }
  float inv = 1.0f / s;
  float o0 = 0.0f, o1 = 0.0f;
#pragma unroll
  for (int j = 0; j < 16; ++j) {
    float a = e[j] * inv;
    o0 += a * t0a[j];
    o1 += a * t1a[j];
  }
  out[g * 128 + lane] = o0;
  out[g * 128 + lane + 64] = o1;
}

// ---------------------------------------------------------------------------
extern "C" void kernel_launch(void* const* d_in, const int* in_sizes, int n_in,
                              void* d_out, int out_size, void* d_ws,
                              size_t ws_size, hipStream_t stream) {
  const float* x = (const float*)d_in[0];
  const float* pos = (const float*)d_in[1];
  const float* coords = (const float*)d_in[2];
  const float* gamma = (const float*)d_in[3];
  const float* beta = (const float*)d_in[4];
  const float* Wa1 = (const float*)d_in[5];
  const float* ba1 = (const float*)d_in[6];
  const float* Wa2 = (const float*)d_in[7];
  const float* ba2 = (const float*)d_in[8];
  const float* Wf1 = (const float*)d_in[9];
  const float* bf1 = (const float*)d_in[10];
  float* out = (float*)d_out;

  char* ws = (char*)d_ws;
  float* xp = (float*)ws;                                 // [0,16MB)
  float* SN = (float*)(ws + (size_t)16 * 1024 * 1024);    // [16,80MB)
  // partial kNN buffers alias the SN region (SN written only after merge)
  float* pd = (float*)(ws + (size_t)16 * 1024 * 1024);    // 16MB
  int* pi = (int*)(ws + (size_t)32 * 1024 * 1024);        // 16MB
  float* Wcat = (float*)(ws + (size_t)80 * 1024 * 1024);  // 256KB
  int* idx = (int*)(ws + (size_t)80 * 1024 * 1024 + 512 * 1024);  // 2MB

  k_lnpos<<<8192, 256, 0, stream>>>(x, pos, gamma, beta, xp);
  k_wcat<<<256, 256, 0, stream>>>(Wa1, Wf1, Wcat);
  k_knn_part<<<B_ * 16 * NPART, 256, 0, stream>>>(coords, pd, pi);
  k_knn_merge<<<128, 256, 0, stream>>>(pd, pi, idx);
  k_gemm<<<4096, 256, 0, stream>>>(xp, Wcat, SN);
  k_attn<<<8192, 256, 0, stream>>>(SN, idx, ba1, bf1, Wa2, ba2, out);
}

// Round 3
// 281.916 us; speedup vs baseline: 5.3209x; 1.9209x over previous
//
#include <hip/hip_runtime.h>

#define B_ 8
#define K_ 4096
#define C_ 128
#define KN 16

// ---------------------------------------------------------------------------
// Kernel 1: LayerNorm(x)*gamma+beta + pos_embed -> xp  [32768, 128]
// ---------------------------------------------------------------------------
__global__ __launch_bounds__(256) void k_lnpos(
    const float* __restrict__ x, const float* __restrict__ pos,
    const float* __restrict__ gamma, const float* __restrict__ beta,
    float* __restrict__ xp) {
  int wave = threadIdx.x >> 6;
  int lane = threadIdx.x & 63;
  size_t row = (size_t)blockIdx.x * 4 + wave;
  const float* xr = x + row * C_;
  const float* pr = pos + row * C_;
  float a = xr[lane], b = xr[lane + 64];
  float s = a + b;
#pragma unroll
  for (int o = 1; o < 64; o <<= 1) s += __shfl_xor(s, o);
  float mu = s * (1.0f / 128.0f);
  float da = a - mu, db = b - mu;
  float v = da * da + db * db;
#pragma unroll
  for (int o = 1; o < 64; o <<= 1) v += __shfl_xor(v, o);
  float rstd = rsqrtf(v * (1.0f / 128.0f) + 1e-5f);
  float xn0 = da * rstd * gamma[lane] + beta[lane];
  float xn1 = db * rstd * gamma[lane + 64] + beta[lane + 64];
  xp[row * C_ + lane] = xn0 + pr[lane];
  xp[row * C_ + lane + 64] = xn1 + pr[lane + 64];
}

// ---------------------------------------------------------------------------
// Kernel 2: build Wcat [128, 512]
// ---------------------------------------------------------------------------
__global__ void k_wcat(const float* __restrict__ Wa1,
                       const float* __restrict__ Wf1,
                       float* __restrict__ Wcat) {
  int i = blockIdx.x * blockDim.x + threadIdx.x;  // 0..65535
  int r = i >> 9;
  int q = i & 511;
  float v;
  if (q < 128)
    v = Wa1[r * 128 + q];
  else if (q < 256)
    v = Wf1[r * 128 + (q - 128)] - Wf1[(128 + r) * 128 + (q - 128)];
  else if (q < 384)
    v = Wa1[(128 + r) * 128 + (q - 256)];
  else
    v = Wf1[(128 + r) * 128 + (q - 384)];
  Wcat[i] = v;
}

// ---------------------------------------------------------------------------
// Kernel 3: exact kNN, wave-per-query bound/gather/sort.
// Reference-exact distance bits: d = (xx_i + xx_j) + (-2*dot), rn ops.
// ---------------------------------------------------------------------------
__device__ __forceinline__ float dist_exact(float4 q, float4 c) {
  float dot = __fadd_rn(__fadd_rn(__fmul_rn(q.x, c.x), __fmul_rn(q.y, c.y)),
                        __fmul_rn(q.z, c.z));
  return __fadd_rn(__fadd_rn(q.w, c.w), __fmul_rn(-2.0f, dot));
}

__global__ __launch_bounds__(256) void k_knn2(const float* __restrict__ coords,
                                              int* __restrict__ idx) {
  __shared__ float4 cc[K_];            // 64 KB: x,y,z,xx
  __shared__ uint2 cbuf[4][4][64];     // per-wave, per-subquery gather buffer
  int b = blockIdx.x >> 6;             // 64 blocks per batch
  int qg = blockIdx.x & 63;            // query group of 64
  const float* cb = coords + (size_t)b * K_ * 3;
  for (int t = threadIdx.x; t < K_; t += 256) {
    float px = cb[t * 3], py = cb[t * 3 + 1], pz = cb[t * 3 + 2];
    float w = __fadd_rn(__fadd_rn(__fmul_rn(px, px), __fmul_rn(py, py)),
                        __fmul_rn(pz, pz));
    cc[t] = make_float4(px, py, pz, w);
  }
  __syncthreads();
  int wave = threadIdx.x >> 6, lane = threadIdx.x & 63;
  unsigned long long lmask_lt = (lane == 63) ? 0x7fffffffffffffffull
                                             : ((1ull << lane) - 1ull);

  for (int grp = 0; grp < 4; ++grp) {
    int qbase = qg * 64 + wave * 16 + grp * 4;
    float4 Q[4];
#pragma unroll
    for (int qq = 0; qq < 4; ++qq) Q[qq] = cc[qbase + qq];

    // ---- pass A: per-lane min over its 64-candidate slice, per query ----
    float m0 = 1e30f, m1 = 1e30f, m2 = 1e30f, m3 = 1e30f;
    for (int it = 0; it < 64; ++it) {
      int j = (it << 6) + lane;
      float4 c = cc[j];
      float d0 = dist_exact(Q[0], c);
      float d1 = dist_exact(Q[1], c);
      float d2 = dist_exact(Q[2], c);
      float d3 = dist_exact(Q[3], c);
      if (j == qbase + 0) d0 = 1e30f;
      if (j == qbase + 1) d1 = 1e30f;
      if (j == qbase + 2) d2 = 1e30f;
      if (j == qbase + 3) d3 = 1e30f;
      m0 = fminf(m0, d0);
      m1 = fminf(m1, d1);
      m2 = fminf(m2, d2);
      m3 = fminf(m3, d3);
    }
    // ---- bound u[qq] = 16th smallest of the 64 lane-minima ----
    float ub[4];
    float mv[4] = {m0, m1, m2, m3};
#pragma unroll
    for (int qq = 0; qq < 4; ++qq) {
      float v = mv[qq];
#pragma unroll
      for (int k = 2; k <= 64; k <<= 1) {
#pragma unroll
        for (int jj = k >> 1; jj >= 1; jj >>= 1) {
          float o = __shfl_xor(v, jj);
          bool amHigh = (lane & jj) != 0;
          bool up = (lane & k) != 0;
          bool gt = v > o;
          bool take = (amHigh ? !gt : gt) ^ up;
          v = take ? o : v;
        }
      }
      ub[qq] = __shfl(v, 15);
    }

    // ---- pass B: gather all candidates with d <= u ----
    unsigned cnt[4] = {0u, 0u, 0u, 0u};
    for (int it = 0; it < 64; ++it) {
      int j = (it << 6) + lane;
      float4 c = cc[j];
#pragma unroll
      for (int qq = 0; qq < 4; ++qq) {
        float d = dist_exact(Q[qq], c);
        bool pass = (d <= ub[qq]) && (j != qbase + qq);
        unsigned long long mask = __ballot(pass);
        if (mask) {
          if (pass) {
            unsigned pos = cnt[qq] + (unsigned)__popcll(mask & lmask_lt);
            if (pos < 64u) cbuf[wave][qq][pos] = make_uint2(__float_as_uint(d), (unsigned)j);
          }
          cnt[qq] += (unsigned)__popcll(mask);
        }
      }
    }
    __asm__ volatile("s_waitcnt lgkmcnt(0)" ::: "memory");

    // ---- pass C: exact lex sort (d asc, idx asc) of gathered, take 16 ----
#pragma unroll
    for (int qq = 0; qq < 4; ++qq) {
      unsigned m = cnt[qq] < 64u ? cnt[qq] : 64u;
      float dC = 1e30f;
      int iC = 0x7fffffff;
      if (lane < (int)m) {
        uint2 e = cbuf[wave][qq][lane];
        dC = __uint_as_float(e.x);
        iC = (int)e.y;
      }
#pragma unroll
      for (int k = 2; k <= 64; k <<= 1) {
#pragma unroll
        for (int jj = k >> 1; jj >= 1; jj >>= 1) {
          float od = __shfl_xor(dC, jj);
          int oi = __shfl_xor(iC, jj);
          bool amHigh = (lane & jj) != 0;
          bool up = (lane & k) != 0;
          bool gt = (dC > od) || (dC == od && iC > oi);
          bool take = (amHigh ? !gt : gt) ^ up;
          dC = take ? od : dC;
          iC = take ? oi : iC;
        }
      }
      if (lane < KN)
        idx[((size_t)b * K_ + (qbase + qq)) * KN + lane] = iC;
    }
  }
}

// ---------------------------------------------------------------------------
// Kernel 4: fp32 GEMM  SN[32768,512] = xp[32768,128] @ Wcat[128,512]
// ---------------------------------------------------------------------------
__global__ __launch_bounds__(256) void k_gemm(const float* __restrict__ A,
                                              const float* __restrict__ Bw,
                                              float* __restrict__ Cm) {
  __shared__ float lA[128][64];  // [k][m]
  __shared__ float lB[128][64];  // [k][n]
  int tn = blockIdx.x & 7;
  int tmb = blockIdx.x >> 3;
  int m0 = tmb * 64;
  int n0 = tn * 64;
  int t = threadIdx.x;

  {  // stage A (transposed)
    int tr = t >> 2, tq = t & 3;
    const float* ap = A + (size_t)(m0 + tr) * 128;
#pragma unroll
    for (int u = 0; u < 8; ++u) {
      int c4 = (tq * 8 + u) * 4;
      float4 av = *(const float4*)(ap + c4);
      lA[c4 + 0][tr] = av.x;
      lA[c4 + 1][tr] = av.y;
      lA[c4 + 2][tr] = av.z;
      lA[c4 + 3][tr] = av.w;
    }
  }
  {  // stage B
    int tr = t >> 1, tq = t & 1;
    const float* bp = Bw + (size_t)tr * 512 + n0;
#pragma unroll
    for (int u = 0; u < 8; ++u) {
      int c4 = (tq * 8 + u) * 4;
      float4 bv = *(const float4*)(bp + c4);
      *(float4*)&lB[tr][c4] = bv;
    }
  }
  __syncthreads();

  int ty = t >> 4, tx = t & 15;
  int mb = ty * 4, nb = tx * 4;
  float acc[4][4];
#pragma unroll
  for (int i = 0; i < 4; ++i)
#pragma unroll
    for (int j = 0; j < 4; ++j) acc[i][j] = 0.0f;

#pragma unroll 4
  for (int k = 0; k < 128; ++k) {
    float4 av = *(float4*)&lA[k][mb];
    float4 bv = *(float4*)&lB[k][nb];
    float a4[4] = {av.x, av.y, av.z, av.w};
    float b4[4] = {bv.x, bv.y, bv.z, bv.w};
#pragma unroll
    for (int i = 0; i < 4; ++i)
#pragma unroll
      for (int j = 0; j < 4; ++j) acc[i][j] += a4[i] * b4[j];
  }

#pragma unroll
  for (int i = 0; i < 4; ++i) {
    size_t row = (size_t)(m0 + mb + i);
    float4 r = make_float4(acc[i][0], acc[i][1], acc[i][2], acc[i][3]);
    *(float4*)(Cm + row * 512 + n0 + nb) = r;
  }
}

// ---------------------------------------------------------------------------
// Kernel 5: attention aggregate. One wave per point.
// SN cols: [0:128]=S_a, [128:256]=S_f, [256:384]=N_a, [384:512]=N_f
// ---------------------------------------------------------------------------
__global__ __launch_bounds__(256) void k_attn(
    const float* __restrict__ SN, const int* __restrict__ idx,
    const float* __restrict__ b_a1, const float* __restrict__ b_f1,
    const float* __restrict__ W_a2, const float* __restrict__ b_a2,
    float* __restrict__ out) {
  int wave = threadIdx.x >> 6, lane = threadIdx.x & 63;
  size_t g = (size_t)blockIdx.x * 4 + wave;
  int b = (int)(g >> 12);
  const float* sr = SN + g * 512;
  float s_a0 = sr[lane], s_a1 = sr[lane + 64];
  float s_f0 = sr[128 + lane], s_f1 = sr[128 + lane + 64];
  float ba0 = b_a1[lane], ba1 = b_a1[lane + 64];
  float bf0 = b_f1[lane], bf1 = b_f1[lane + 64];
  float w20 = W_a2[lane], w21 = W_a2[lane + 64];
  float ba2 = b_a2[0];
  const int* ip = idx + g * 16;
  float lg[16], t0a[16], t1a[16];
#pragma unroll
  for (int j = 0; j < 16; ++j) {
    int n = ip[j];
    const float* nr = SN + ((size_t)((b << 12) + n)) * 512 + 256;
    float na0 = nr[lane], na1 = nr[lane + 64];
    float nf0 = nr[128 + lane], nf1 = nr[128 + lane + 64];
    float h0 = s_a0 + na0 + ba0;
    h0 = h0 >= 0.0f ? h0 : 0.2f * h0;
    float h1 = s_a1 + na1 + ba1;
    h1 = h1 >= 0.0f ? h1 : 0.2f * h1;
    float t0 = s_f0 + nf0 + bf0;
    t0 = t0 >= 0.0f ? t0 : 0.2f * t0;
    float t1 = s_f1 + nf1 + bf1;
    t1 = t1 >= 0.0f ? t1 : 0.2f * t1;
    float pl = h0 * w20 + h1 * w21;
#pragma unroll
    for (int o = 1; o < 64; o <<= 1) pl += __shfl_xor(pl, o);
    lg[j] = pl + ba2;
    t0a[j] = t0;
    t1a[j] = t1;
  }
  float m = lg[0];
#pragma unroll
  for (int j = 1; j < 16; ++j) m = fmaxf(m, lg[j]);
  float s = 0.0f;
  float e[16];
#pragma unroll
  for (int j = 0; j < 16; ++j) {
    e[j] = expf(lg[j] - m);
    s += e[j];
  }
  float inv = 1.0f / s;
  float o0 = 0.0f, o1 = 0.0f;
#pragma unroll
  for (int j = 0; j < 16; ++j) {
    float a = e[j] * inv;
    o0 += a * t0a[j];
    o1 += a * t1a[j];
  }
  out[g * 128 + lane] = o0;
  out[g * 128 + lane + 64] = o1;
}

// ---------------------------------------------------------------------------
extern "C" void kernel_launch(void* const* d_in, const int* in_sizes, int n_in,
                              void* d_out, int out_size, void* d_ws,
                              size_t ws_size, hipStream_t stream) {
  const float* x = (const float*)d_in[0];
  const float* pos = (const float*)d_in[1];
  const float* coords = (const float*)d_in[2];
  const float* gamma = (const float*)d_in[3];
  const float* beta = (const float*)d_in[4];
  const float* Wa1 = (const float*)d_in[5];
  const float* ba1 = (const float*)d_in[6];
  const float* Wa2 = (const float*)d_in[7];
  const float* ba2 = (const float*)d_in[8];
  const float* Wf1 = (const float*)d_in[9];
  const float* bf1 = (const float*)d_in[10];
  float* out = (float*)d_out;

  char* ws = (char*)d_ws;
  float* xp = (float*)ws;                                 // [0,16MB)
  float* SN = (float*)(ws + (size_t)16 * 1024 * 1024);    // [16,80MB)
  float* Wcat = (float*)(ws + (size_t)80 * 1024 * 1024);  // 256KB
  int* idx = (int*)(ws + (size_t)80 * 1024 * 1024 + 512 * 1024);  // 2MB

  k_lnpos<<<8192, 256, 0, stream>>>(x, pos, gamma, beta, xp);
  k_wcat<<<256, 256, 0, stream>>>(Wa1, Wf1, Wcat);
  k_knn2<<<B_ * 64, 256, 0, stream>>>(coords, idx);
  k_gemm<<<4096, 256, 0, stream>>>(xp, Wcat, SN);
  k_attn<<<8192, 256, 0, stream>>>(SN, idx, ba1, bf1, Wa2, ba2, out);
}

// Round 4
// 245.082 us; speedup vs baseline: 6.1206x; 1.1503x over previous
//
#include <hip/hip_runtime.h>

#define B_ 8
#define K_ 4096
#define C_ 128
#define KN 16

// ---------------------------------------------------------------------------
// Kernel 1: LayerNorm(x)*gamma+beta + pos_embed -> xp  [32768, 128]
// ---------------------------------------------------------------------------
__global__ __launch_bounds__(256) void k_lnpos(
    const float* __restrict__ x, const float* __restrict__ pos,
    const float* __restrict__ gamma, const float* __restrict__ beta,
    float* __restrict__ xp) {
  int wave = threadIdx.x >> 6;
  int lane = threadIdx.x & 63;
  size_t row = (size_t)blockIdx.x * 4 + wave;
  const float* xr = x + row * C_;
  const float* pr = pos + row * C_;
  float a = xr[lane], b = xr[lane + 64];
  float s = a + b;
#pragma unroll
  for (int o = 1; o < 64; o <<= 1) s += __shfl_xor(s, o);
  float mu = s * (1.0f / 128.0f);
  float da = a - mu, db = b - mu;
  float v = da * da + db * db;
#pragma unroll
  for (int o = 1; o < 64; o <<= 1) v += __shfl_xor(v, o);
  float rstd = rsqrtf(v * (1.0f / 128.0f) + 1e-5f);
  float xn0 = da * rstd * gamma[lane] + beta[lane];
  float xn1 = db * rstd * gamma[lane + 64] + beta[lane + 64];
  xp[row * C_ + lane] = xn0 + pr[lane];
  xp[row * C_ + lane + 64] = xn1 + pr[lane + 64];
}

// ---------------------------------------------------------------------------
// Kernel 2: build Wcat [128, 512]
// ---------------------------------------------------------------------------
__global__ void k_wcat(const float* __restrict__ Wa1,
                       const float* __restrict__ Wf1,
                       float* __restrict__ Wcat) {
  int i = blockIdx.x * blockDim.x + threadIdx.x;  // 0..65535
  int r = i >> 9;
  int q = i & 511;
  float v;
  if (q < 128)
    v = Wa1[r * 128 + q];
  else if (q < 256)
    v = Wf1[r * 128 + (q - 128)] - Wf1[(128 + r) * 128 + (q - 128)];
  else if (q < 384)
    v = Wa1[(128 + r) * 128 + (q - 256)];
  else
    v = Wf1[(128 + r) * 128 + (q - 384)];
  Wcat[i] = v;
}

// ---------------------------------------------------------------------------
// Kernel 2b: pack coords -> [x,y,z,xx] float4 (exact xx bits)
// ---------------------------------------------------------------------------
__global__ __launch_bounds__(256) void k_pack(const float* __restrict__ coords,
                                              float4* __restrict__ cc4) {
  int i = blockIdx.x * 256 + threadIdx.x;  // 0..32767
  float px = coords[i * 3], py = coords[i * 3 + 1], pz = coords[i * 3 + 2];
  float w = __fadd_rn(__fadd_rn(__fmul_rn(px, px), __fmul_rn(py, py)),
                      __fmul_rn(pz, pz));
  cc4[i] = make_float4(px, py, pz, w);
}

// ---------------------------------------------------------------------------
// Kernel 3: exact kNN, wave-per-4-queries, candidates streamed from L2.
// Reference-exact distance bits: d = (xx_i + xx_j) + (-2*dot), rn ops.
// ---------------------------------------------------------------------------
__device__ __forceinline__ float dist_exact(float4 q, float4 c) {
  float dot = __fadd_rn(__fadd_rn(__fmul_rn(q.x, c.x), __fmul_rn(q.y, c.y)),
                        __fmul_rn(q.z, c.z));
  return __fadd_rn(__fadd_rn(q.w, c.w), __fmul_rn(-2.0f, dot));
}

__global__ __launch_bounds__(256) void k_knn3(const float4* __restrict__ cc4,
                                              int* __restrict__ idx) {
  __shared__ uint2 cbuf[4][4][64];  // per-wave, per-subquery gather buffer
  int wave = threadIdx.x >> 6, lane = threadIdx.x & 63;
  int gw = blockIdx.x * 4 + wave;  // global wave id, 0..8191
  int b = gw >> 10;                // 1024 waves per batch
  int qbase = (gw & 1023) * 4;
  const float4* cb = cc4 + (size_t)b * K_;
  unsigned long long lmask_lt = (lane == 63) ? 0x7fffffffffffffffull
                                             : ((1ull << lane) - 1ull);
  float4 Q[4];
#pragma unroll
  for (int qq = 0; qq < 4; ++qq) Q[qq] = cb[qbase + qq];

  // ---- pass A: per-lane min over its 64-candidate slice, per query ----
  float m0 = 1e30f, m1 = 1e30f, m2 = 1e30f, m3 = 1e30f;
#pragma unroll 4
  for (int it = 0; it < 64; ++it) {
    int j = (it << 6) + lane;
    float4 c = cb[j];
    float d0 = dist_exact(Q[0], c);
    float d1 = dist_exact(Q[1], c);
    float d2 = dist_exact(Q[2], c);
    float d3 = dist_exact(Q[3], c);
    if (j == qbase + 0) d0 = 1e30f;
    if (j == qbase + 1) d1 = 1e30f;
    if (j == qbase + 2) d2 = 1e30f;
    if (j == qbase + 3) d3 = 1e30f;
    m0 = fminf(m0, d0);
    m1 = fminf(m1, d1);
    m2 = fminf(m2, d2);
    m3 = fminf(m3, d3);
  }
  // ---- bound u[qq] = 16th smallest of the 64 lane-minima ----
  float ub[4];
  float mv[4] = {m0, m1, m2, m3};
#pragma unroll
  for (int qq = 0; qq < 4; ++qq) {
    float v = mv[qq];
#pragma unroll
    for (int k = 2; k <= 64; k <<= 1) {
#pragma unroll
      for (int jj = k >> 1; jj >= 1; jj >>= 1) {
        float o = __shfl_xor(v, jj);
        bool amHigh = (lane & jj) != 0;
        bool up = (lane & k) != 0;
        bool gt = v > o;
        bool take = (amHigh ? !gt : gt) ^ up;
        v = take ? o : v;
      }
    }
    ub[qq] = __shfl(v, 15);
  }

  // ---- pass B: gather all candidates with d <= u ----
  unsigned cnt[4] = {0u, 0u, 0u, 0u};
#pragma unroll 2
  for (int it = 0; it < 64; ++it) {
    int j = (it << 6) + lane;
    float4 c = cb[j];
#pragma unroll
    for (int qq = 0; qq < 4; ++qq) {
      float d = dist_exact(Q[qq], c);
      bool pass = (d <= ub[qq]) && (j != qbase + qq);
      unsigned long long mask = __ballot(pass);
      if (mask) {
        if (pass) {
          unsigned pos = cnt[qq] + (unsigned)__popcll(mask & lmask_lt);
          if (pos < 64u)
            cbuf[wave][qq][pos] = make_uint2(__float_as_uint(d), (unsigned)j);
        }
        cnt[qq] += (unsigned)__popcll(mask);
      }
    }
  }
  __asm__ volatile("s_waitcnt lgkmcnt(0)" ::: "memory");

  // ---- pass C: exact lex sort (d asc, idx asc) of gathered, take 16 ----
#pragma unroll
  for (int qq = 0; qq < 4; ++qq) {
    unsigned m = cnt[qq] < 64u ? cnt[qq] : 64u;
    float dC = 1e30f;
    int iC = 0x7fffffff;
    if (lane < (int)m) {
      uint2 e = cbuf[wave][qq][lane];
      dC = __uint_as_float(e.x);
      iC = (int)e.y;
    }
#pragma unroll
    for (int k = 2; k <= 64; k <<= 1) {
#pragma unroll
      for (int jj = k >> 1; jj >= 1; jj >>= 1) {
        float od = __shfl_xor(dC, jj);
        int oi = __shfl_xor(iC, jj);
        bool amHigh = (lane & jj) != 0;
        bool up = (lane & k) != 0;
        bool gt = (dC > od) || (dC == od && iC > oi);
        bool take = (amHigh ? !gt : gt) ^ up;
        dC = take ? od : dC;
        iC = take ? oi : iC;
      }
    }
    if (lane < KN)
      idx[((size_t)b * K_ + (qbase + qq)) * KN + lane] = iC;
  }
}

// ---------------------------------------------------------------------------
// Kernel 4: fp32 GEMM  SN[32768,512] = xp[32768,128] @ Wcat[128,512]
// ---------------------------------------------------------------------------
__global__ __launch_bounds__(256) void k_gemm(const float* __restrict__ A,
                                              const float* __restrict__ Bw,
                                              float* __restrict__ Cm) {
  __shared__ float lA[128][64];  // [k][m]
  __shared__ float lB[128][64];  // [k][n]
  int tn = blockIdx.x & 7;
  int tmb = blockIdx.x >> 3;
  int m0 = tmb * 64;
  int n0 = tn * 64;
  int t = threadIdx.x;

  {  // stage A (transposed)
    int tr = t >> 2, tq = t & 3;
    const float* ap = A + (size_t)(m0 + tr) * 128;
#pragma unroll
    for (int u = 0; u < 8; ++u) {
      int c4 = (tq * 8 + u) * 4;
      float4 av = *(const float4*)(ap + c4);
      lA[c4 + 0][tr] = av.x;
      lA[c4 + 1][tr] = av.y;
      lA[c4 + 2][tr] = av.z;
      lA[c4 + 3][tr] = av.w;
    }
  }
  {  // stage B
    int tr = t >> 1, tq = t & 1;
    const float* bp = Bw + (size_t)tr * 512 + n0;
#pragma unroll
    for (int u = 0; u < 8; ++u) {
      int c4 = (tq * 8 + u) * 4;
      float4 bv = *(const float4*)(bp + c4);
      *(float4*)&lB[tr][c4] = bv;
    }
  }
  __syncthreads();

  int ty = t >> 4, tx = t & 15;
  int mb = ty * 4, nb = tx * 4;
  float acc[4][4];
#pragma unroll
  for (int i = 0; i < 4; ++i)
#pragma unroll
    for (int j = 0; j < 4; ++j) acc[i][j] = 0.0f;

#pragma unroll 4
  for (int k = 0; k < 128; ++k) {
    float4 av = *(float4*)&lA[k][mb];
    float4 bv = *(float4*)&lB[k][nb];
    float a4[4] = {av.x, av.y, av.z, av.w};
    float b4[4] = {bv.x, bv.y, bv.z, bv.w};
#pragma unroll
    for (int i = 0; i < 4; ++i)
#pragma unroll
      for (int j = 0; j < 4; ++j) acc[i][j] += a4[i] * b4[j];
  }

#pragma unroll
  for (int i = 0; i < 4; ++i) {
    size_t row = (size_t)(m0 + mb + i);
    float4 r = make_float4(acc[i][0], acc[i][1], acc[i][2], acc[i][3]);
    *(float4*)(Cm + row * 512 + n0 + nb) = r;
  }
}

// ---------------------------------------------------------------------------
// Kernel 5: attention aggregate. One wave per point.
// SN cols: [0:128]=S_a, [128:256]=S_f, [256:384]=N_a, [384:512]=N_f
// ---------------------------------------------------------------------------
__global__ __launch_bounds__(256) void k_attn(
    const float* __restrict__ SN, const int* __restrict__ idx,
    const float* __restrict__ b_a1, const float* __restrict__ b_f1,
    const float* __restrict__ W_a2, const float* __restrict__ b_a2,
    float* __restrict__ out) {
  int wave = threadIdx.x >> 6, lane = threadIdx.x & 63;
  size_t g = (size_t)blockIdx.x * 4 + wave;
  int b = (int)(g >> 12);
  const float* sr = SN + g * 512;
  float s_a0 = sr[lane], s_a1 = sr[lane + 64];
  float s_f0 = sr[128 + lane], s_f1 = sr[128 + lane + 64];
  float ba0 = b_a1[lane], ba1 = b_a1[lane + 64];
  float bf0 = b_f1[lane], bf1 = b_f1[lane + 64];
  float w20 = W_a2[lane], w21 = W_a2[lane + 64];
  float ba2 = b_a2[0];
  const int* ip = idx + g * 16;
  float lg[16], t0a[16], t1a[16];
#pragma unroll
  for (int j = 0; j < 16; ++j) {
    int n = ip[j];
    const float* nr = SN + ((size_t)((b << 12) + n)) * 512 + 256;
    float na0 = nr[lane], na1 = nr[lane + 64];
    float nf0 = nr[128 + lane], nf1 = nr[128 + lane + 64];
    float h0 = s_a0 + na0 + ba0;
    h0 = h0 >= 0.0f ? h0 : 0.2f * h0;
    float h1 = s_a1 + na1 + ba1;
    h1 = h1 >= 0.0f ? h1 : 0.2f * h1;
    float t0 = s_f0 + nf0 + bf0;
    t0 = t0 >= 0.0f ? t0 : 0.2f * t0;
    float t1 = s_f1 + nf1 + bf1;
    t1 = t1 >= 0.0f ? t1 : 0.2f * t1;
    float pl = h0 * w20 + h1 * w21;
#pragma unroll
    for (int o = 1; o < 64; o <<= 1) pl += __shfl_xor(pl, o);
    lg[j] = pl + ba2;
    t0a[j] = t0;
    t1a[j] = t1;
  }
  float m = lg[0];
#pragma unroll
  for (int j = 1; j < 16; ++j) m = fmaxf(m, lg[j]);
  float s = 0.0f;
  float e[16];
#pragma unroll
  for (int j = 0; j < 16; ++j) {
    e[j] = expf(lg[j] - m);
    s += e[j];
  }
  float inv = 1.0f / s;
  float o0 = 0.0f, o1 = 0.0f;
#pragma unroll
  for (int j = 0; j < 16; ++j) {
    float a = e[j] * inv;
    o0 += a * t0a[j];
    o1 += a * t1a[j];
  }
  out[g * 128 + lane] = o0;
  out[g * 128 + lane + 64] = o1;
}

// ---------------------------------------------------------------------------
extern "C" void kernel_launch(void* const* d_in, const int* in_sizes, int n_in,
                              void* d_out, int out_size, void* d_ws,
                              size_t ws_size, hipStream_t stream) {
  const float* x = (const float*)d_in[0];
  const float* pos = (const float*)d_in[1];
  const float* coords = (const float*)d_in[2];
  const float* gamma = (const float*)d_in[3];
  const float* beta = (const float*)d_in[4];
  const float* Wa1 = (const float*)d_in[5];
  const float* ba1 = (const float*)d_in[6];
  const float* Wa2 = (const float*)d_in[7];
  const float* ba2 = (const float*)d_in[8];
  const float* Wf1 = (const float*)d_in[9];
  const float* bf1 = (const float*)d_in[10];
  float* out = (float*)d_out;

  char* ws = (char*)d_ws;
  float* xp = (float*)ws;                                 // [0,16MB)
  float* SN = (float*)(ws + (size_t)16 * 1024 * 1024);    // [16,80MB)
  float* Wcat = (float*)(ws + (size_t)80 * 1024 * 1024);  // 256KB
  int* idx = (int*)(ws + (size_t)80 * 1024 * 1024 + 512 * 1024);  // 2MB
  float4* cc4 = (float4*)(ws + (size_t)80 * 1024 * 1024 + 2560 * 1024);  // 512KB

  k_pack<<<128, 256, 0, stream>>>(coords, cc4);
  k_lnpos<<<8192, 256, 0, stream>>>(x, pos, gamma, beta, xp);
  k_wcat<<<256, 256, 0, stream>>>(Wa1, Wf1, Wcat);
  k_knn3<<<B_ * 256, 256, 0, stream>>>(cc4, idx);
  k_gemm<<<4096, 256, 0, stream>>>(xp, Wcat, SN);
  k_attn<<<8192, 256, 0, stream>>>(SN, idx, ba1, bf1, Wa2, ba2, out);
}

// Round 5
// 162.789 us; speedup vs baseline: 9.2147x; 1.5055x over previous
//
#include <hip/hip_runtime.h>

#define B_ 8
#define K_ 4096
#define C_ 128
#define KN 16

typedef __attribute__((ext_vector_type(8))) short bf16x8;
typedef __attribute__((ext_vector_type(4))) float f32x4;

__device__ __forceinline__ unsigned short f2bf(float f) {
  unsigned u = __float_as_uint(f);
  unsigned r = (u + 0x7FFFu + ((u >> 16) & 1u)) >> 16;
  return (unsigned short)r;
}
__device__ __forceinline__ float bfl(unsigned u) {
  return __uint_as_float(u << 16);
}
__device__ __forceinline__ float bfh(unsigned u) {
  return __uint_as_float(u & 0xffff0000u);
}

// ---------------------------------------------------------------------------
// Kernel 1: LayerNorm(x)*gamma+beta + pos_embed -> A bf16 [32768,128]
// pair mapping: lane handles channels (2l, 2l+1)
// ---------------------------------------------------------------------------
__global__ __launch_bounds__(256) void k_lnpos(
    const float* __restrict__ x, const float* __restrict__ pos,
    const float* __restrict__ gamma, const float* __restrict__ beta,
    unsigned short* __restrict__ A) {
  int wave = threadIdx.x >> 6;
  int lane = threadIdx.x & 63;
  size_t row = (size_t)blockIdx.x * 4 + wave;
  const float2* xr = (const float2*)(x + row * C_);
  const float2* pr = (const float2*)(pos + row * C_);
  float2 a = xr[lane];
  float s = a.x + a.y;
#pragma unroll
  for (int o = 1; o < 64; o <<= 1) s += __shfl_xor(s, o);
  float mu = s * (1.0f / 128.0f);
  float dx = a.x - mu, dy = a.y - mu;
  float v = dx * dx + dy * dy;
#pragma unroll
  for (int o = 1; o < 64; o <<= 1) v += __shfl_xor(v, o);
  float rstd = rsqrtf(v * (1.0f / 128.0f) + 1e-5f);
  float2 gm = ((const float2*)gamma)[lane];
  float2 bt = ((const float2*)beta)[lane];
  float2 pp = pr[lane];
  float o0 = dx * rstd * gm.x + bt.x + pp.x;
  float o1 = dy * rstd * gm.y + bt.y + pp.y;
  ushort2 o = make_ushort2(f2bf(o0), f2bf(o1));
  *(ushort2*)(A + row * C_ + 2 * lane) = o;
}

// ---------------------------------------------------------------------------
// Kernel 2: build WcatT bf16 [512][128] (transposed combined weights)
// out-col q: 0:128=W_a1 top (S_a), 128:256=Wf top - Wf bot (S_f),
//            256:384=W_a1 bot (N_a), 384:512=Wf bot (N_f)
// ---------------------------------------------------------------------------
__global__ void k_wcatT(const float* __restrict__ Wa1,
                        const float* __restrict__ Wf1,
                        unsigned short* __restrict__ WT) {
  int i = blockIdx.x * blockDim.x + threadIdx.x;  // 0..65535
  int q = i >> 7;
  int r = i & 127;
  float v;
  if (q < 128)
    v = Wa1[r * 128 + q];
  else if (q < 256)
    v = Wf1[r * 128 + (q - 128)] - Wf1[(128 + r) * 128 + (q - 128)];
  else if (q < 384)
    v = Wa1[(128 + r) * 128 + (q - 256)];
  else
    v = Wf1[(128 + r) * 128 + (q - 384)];
  WT[i] = f2bf(v);
}

// ---------------------------------------------------------------------------
// Kernel 2b: pack coords -> [x,y,z,xx] float4 (exact xx bits)
// ---------------------------------------------------------------------------
__global__ __launch_bounds__(256) void k_pack(const float* __restrict__ coords,
                                              float4* __restrict__ cc4) {
  int i = blockIdx.x * 256 + threadIdx.x;  // 0..32767
  float px = coords[i * 3], py = coords[i * 3 + 1], pz = coords[i * 3 + 2];
  float w = __fadd_rn(__fadd_rn(__fmul_rn(px, px), __fmul_rn(py, py)),
                      __fmul_rn(pz, pz));
  cc4[i] = make_float4(px, py, pz, w);
}

// ---------------------------------------------------------------------------
// Kernel 3: exact kNN, wave-per-4-queries, candidates streamed from L2.
// pass A uses fast fma distance for the BOUND only (inflated +1e-4);
// pass B/C use reference-exact bits -> identical selected set.
// ---------------------------------------------------------------------------
__device__ __forceinline__ float dist_exact(float4 q, float4 c) {
  float dot = __fadd_rn(__fadd_rn(__fmul_rn(q.x, c.x), __fmul_rn(q.y, c.y)),
                        __fmul_rn(q.z, c.z));
  return __fadd_rn(__fadd_rn(q.w, c.w), __fmul_rn(-2.0f, dot));
}
__device__ __forceinline__ float dist_fast(float4 q, float4 c) {
  float dot = fmaf(q.x, c.x, fmaf(q.y, c.y, q.z * c.z));
  return fmaf(-2.0f, dot, q.w + c.w);
}

__global__ __launch_bounds__(256) void k_knn3(const float4* __restrict__ cc4,
                                              int* __restrict__ idx) {
  __shared__ uint2 cbuf[4][4][64];  // per-wave, per-subquery gather buffer
  int wave = threadIdx.x >> 6, lane = threadIdx.x & 63;
  int gw = blockIdx.x * 4 + wave;  // global wave id, 0..8191
  int b = gw >> 10;                // 1024 waves per batch
  int qbase = (gw & 1023) * 4;
  const float4* cb = cc4 + (size_t)b * K_;
  unsigned long long lmask_lt = (lane == 63) ? 0x7fffffffffffffffull
                                             : ((1ull << lane) - 1ull);
  float4 Q[4];
#pragma unroll
  for (int qq = 0; qq < 4; ++qq) Q[qq] = cb[qbase + qq];

  // ---- pass A: per-lane min (fast dist) over its 64-candidate slice ----
  float m0 = 1e30f, m1 = 1e30f, m2 = 1e30f, m3 = 1e30f;
#pragma unroll 4
  for (int it = 0; it < 64; ++it) {
    int j = (it << 6) + lane;
    float4 c = cb[j];
    float d0 = dist_fast(Q[0], c);
    float d1 = dist_fast(Q[1], c);
    float d2 = dist_fast(Q[2], c);
    float d3 = dist_fast(Q[3], c);
    if (j == qbase + 0) d0 = 1e30f;
    if (j == qbase + 1) d1 = 1e30f;
    if (j == qbase + 2) d2 = 1e30f;
    if (j == qbase + 3) d3 = 1e30f;
    m0 = fminf(m0, d0);
    m1 = fminf(m1, d1);
    m2 = fminf(m2, d2);
    m3 = fminf(m3, d3);
  }
  // ---- bound u[qq] = 16th smallest of the 64 lane-minima, inflated ----
  float ub[4];
  float mv[4] = {m0, m1, m2, m3};
#pragma unroll
  for (int qq = 0; qq < 4; ++qq) {
    float v = mv[qq];
#pragma unroll
    for (int k = 2; k <= 64; k <<= 1) {
#pragma unroll
      for (int jj = k >> 1; jj >= 1; jj >>= 1) {
        float o = __shfl_xor(v, jj);
        bool amHigh = (lane & jj) != 0;
        bool up = (lane & k) != 0;
        bool gt = v > o;
        bool take = (amHigh ? !gt : gt) ^ up;
        v = take ? o : v;
      }
    }
    ub[qq] = __shfl(v, 15) + 1e-4f;
  }

  // ---- pass B: gather all candidates with exact d <= u ----
  unsigned cnt[4] = {0u, 0u, 0u, 0u};
#pragma unroll 2
  for (int it = 0; it < 64; ++it) {
    int j = (it << 6) + lane;
    float4 c = cb[j];
#pragma unroll
    for (int qq = 0; qq < 4; ++qq) {
      float d = dist_exact(Q[qq], c);
      bool pass = (d <= ub[qq]) && (j != qbase + qq);
      unsigned long long mask = __ballot(pass);
      if (mask) {
        if (pass) {
          unsigned pos = cnt[qq] + (unsigned)__popcll(mask & lmask_lt);
          if (pos < 64u)
            cbuf[wave][qq][pos] = make_uint2(__float_as_uint(d), (unsigned)j);
        }
        cnt[qq] += (unsigned)__popcll(mask);
      }
    }
  }
  __asm__ volatile("s_waitcnt lgkmcnt(0)" ::: "memory");

  // ---- pass C: exact lex sort (d asc, idx asc) of gathered, take 16 ----
#pragma unroll
  for (int qq = 0; qq < 4; ++qq) {
    unsigned m = cnt[qq] < 64u ? cnt[qq] : 64u;
    float dC = 1e30f;
    int iC = 0x7fffffff;
    if (lane < (int)m) {
      uint2 e = cbuf[wave][qq][lane];
      dC = __uint_as_float(e.x);
      iC = (int)e.y;
    }
#pragma unroll
    for (int k = 2; k <= 64; k <<= 1) {
#pragma unroll
      for (int jj = k >> 1; jj >= 1; jj >>= 1) {
        float od = __shfl_xor(dC, jj);
        int oi = __shfl_xor(iC, jj);
        bool amHigh = (lane & jj) != 0;
        bool up = (lane & k) != 0;
        bool gt = (dC > od) || (dC == od && iC > oi);
        bool take = (amHigh ? !gt : gt) ^ up;
        dC = take ? od : dC;
        iC = take ? oi : iC;
      }
    }
    if (lane < KN)
      idx[((size_t)b * K_ + (qbase + qq)) * KN + lane] = iC;
  }
}

// ---------------------------------------------------------------------------
// Kernel 4: MFMA GEMM  SN_bf16[32768,512] = A_bf16[32768,128] @ Wcat[128,512]
// BT is WcatT [512][128]. 128x128 tile, 4 waves, each wave 64x64.
// LDS holds B-slice as [n][k] bf16 with (n&7)<<4 XOR swizzle.
// ---------------------------------------------------------------------------
__global__ __launch_bounds__(256) void k_gemm_mfma(
    const unsigned short* __restrict__ A, const unsigned short* __restrict__ BT,
    unsigned short* __restrict__ SN) {
  __shared__ char lB[32768];
  int nb = blockIdx.x & 3;
  int mb = blockIdx.x >> 2;
  int m0 = mb * 128, n0 = nb * 128;
  int t = threadIdx.x;
  {  // stage BT rows n0..n0+127 (32KB linear) with XOR swizzle
    const char* src = (const char*)(BT + (size_t)n0 * 128);
#pragma unroll
    for (int i = 0; i < 8; ++i) {
      int byte = (t + i * 256) * 16;
      int n = byte >> 8;
      int sb = byte ^ ((n & 7) << 4);
      *(float4*)(lB + sb) = *(const float4*)(src + byte);
    }
  }
  __syncthreads();
  int wave = t >> 6, lane = t & 63;
  int wr = wave >> 1, wc = wave & 1;
  int lm = lane & 15, lk = lane >> 4;  // 0..3
  f32x4 z = {0.f, 0.f, 0.f, 0.f};
  f32x4 acc00 = z, acc01 = z, acc02 = z, acc03 = z;
  f32x4 acc10 = z, acc11 = z, acc12 = z, acc13 = z;
  f32x4 acc20 = z, acc21 = z, acc22 = z, acc23 = z;
  f32x4 acc30 = z, acc31 = z, acc32 = z, acc33 = z;
  const char* abase =
      (const char*)A + (size_t)(m0 + wr * 64 + lm) * 256 + lk * 16;
#pragma unroll
  for (int ks = 0; ks < 4; ++ks) {
    bf16x8 af[4], bfr[4];
#pragma unroll
    for (int mt = 0; mt < 4; ++mt)
      af[mt] = *(const bf16x8*)(abase + (size_t)mt * 4096 + ks * 64);
#pragma unroll
    for (int nt = 0; nt < 4; ++nt) {
      int n_local = wc * 64 + nt * 16 + lm;
      int byte = n_local * 256 + ks * 64 + lk * 16;
      byte ^= (n_local & 7) << 4;
      bfr[nt] = *(const bf16x8*)(lB + byte);
    }
    acc00 = __builtin_amdgcn_mfma_f32_16x16x32_bf16(af[0], bfr[0], acc00, 0, 0, 0);
    acc01 = __builtin_amdgcn_mfma_f32_16x16x32_bf16(af[0], bfr[1], acc01, 0, 0, 0);
    acc02 = __builtin_amdgcn_mfma_f32_16x16x32_bf16(af[0], bfr[2], acc02, 0, 0, 0);
    acc03 = __builtin_amdgcn_mfma_f32_16x16x32_bf16(af[0], bfr[3], acc03, 0, 0, 0);
    acc10 = __builtin_amdgcn_mfma_f32_16x16x32_bf16(af[1], bfr[0], acc10, 0, 0, 0);
    acc11 = __builtin_amdgcn_mfma_f32_16x16x32_bf16(af[1], bfr[1], acc11, 0, 0, 0);
    acc12 = __builtin_amdgcn_mfma_f32_16x16x32_bf16(af[1], bfr[2], acc12, 0, 0, 0);
    acc13 = __builtin_amdgcn_mfma_f32_16x16x32_bf16(af[1], bfr[3], acc13, 0, 0, 0);
    acc20 = __builtin_amdgcn_mfma_f32_16x16x32_bf16(af[2], bfr[0], acc20, 0, 0, 0);
    acc21 = __builtin_amdgcn_mfma_f32_16x16x32_bf16(af[2], bfr[1], acc21, 0, 0, 0);
    acc22 = __builtin_amdgcn_mfma_f32_16x16x32_bf16(af[2], bfr[2], acc22, 0, 0, 0);
    acc23 = __builtin_amdgcn_mfma_f32_16x16x32_bf16(af[2], bfr[3], acc23, 0, 0, 0);
    acc30 = __builtin_amdgcn_mfma_f32_16x16x32_bf16(af[3], bfr[0], acc30, 0, 0, 0);
    acc31 = __builtin_amdgcn_mfma_f32_16x16x32_bf16(af[3], bfr[1], acc31, 0, 0, 0);
    acc32 = __builtin_amdgcn_mfma_f32_16x16x32_bf16(af[3], bfr[2], acc32, 0, 0, 0);
    acc33 = __builtin_amdgcn_mfma_f32_16x16x32_bf16(af[3], bfr[3], acc33, 0, 0, 0);
  }
  // epilogue: C[row=(lk*4+r)][col=lm] within each 16x16 frag
  f32x4 accs[4][4] = {{acc00, acc01, acc02, acc03},
                      {acc10, acc11, acc12, acc13},
                      {acc20, acc21, acc22, acc23},
                      {acc30, acc31, acc32, acc33}};
#pragma unroll
  for (int mt = 0; mt < 4; ++mt) {
#pragma unroll
    for (int nt = 0; nt < 4; ++nt) {
#pragma unroll
      for (int r = 0; r < 4; ++r) {
        int row = m0 + wr * 64 + mt * 16 + lk * 4 + r;
        int col = n0 + wc * 64 + nt * 16 + lm;
        SN[(size_t)row * 512 + col] = f2bf(accs[mt][nt][r]);
      }
    }
  }
}

// ---------------------------------------------------------------------------
// Kernel 5: attention aggregate. One wave per point, pair mapping (2l,2l+1).
// SN cols: [0:128]=S_a, [128:256]=S_f, [256:384]=N_a, [384:512]=N_f (bf16)
// ---------------------------------------------------------------------------
__global__ __launch_bounds__(256) void k_attn(
    const unsigned short* __restrict__ SN, const int* __restrict__ idx,
    const float* __restrict__ b_a1, const float* __restrict__ b_f1,
    const float* __restrict__ W_a2, const float* __restrict__ b_a2,
    float* __restrict__ out) {
  int wave = threadIdx.x >> 6, lane = threadIdx.x & 63;
  size_t g = (size_t)blockIdx.x * 4 + wave;
  int b = (int)(g >> 12);
  const unsigned* sr = (const unsigned*)(SN + g * 512);
  unsigned usa = sr[lane], usf = sr[64 + lane];
  float s_a0 = bfl(usa), s_a1 = bfh(usa);
  float s_f0 = bfl(usf), s_f1 = bfh(usf);
  float2 ba = ((const float2*)b_a1)[lane];
  float2 bf = ((const float2*)b_f1)[lane];
  float2 w2 = ((const float2*)W_a2)[lane];
  float ba2 = b_a2[0];
  int nv = 0;
  if (lane < 16) nv = idx[g * 16 + lane];
  float lg[16], t0a[16], t1a[16];
#pragma unroll
  for (int j = 0; j < 16; ++j) {
    int n = __shfl(nv, j);
    const unsigned* nr = (const unsigned*)(SN + ((size_t)((b << 12) + n)) * 512);
    unsigned una = nr[128 + lane];
    unsigned unf = nr[192 + lane];
    float h0 = s_a0 + bfl(una) + ba.x;
    h0 = h0 >= 0.0f ? h0 : 0.2f * h0;
    float h1 = s_a1 + bfh(una) + ba.y;
    h1 = h1 >= 0.0f ? h1 : 0.2f * h1;
    float t0 = s_f0 + bfl(unf) + bf.x;
    t0 = t0 >= 0.0f ? t0 : 0.2f * t0;
    float t1 = s_f1 + bfh(unf) + bf.y;
    t1 = t1 >= 0.0f ? t1 : 0.2f * t1;
    float pl = h0 * w2.x + h1 * w2.y;
#pragma unroll
    for (int o = 1; o < 64; o <<= 1) pl += __shfl_xor(pl, o);
    lg[j] = pl + ba2;
    t0a[j] = t0;
    t1a[j] = t1;
  }
  float m = lg[0];
#pragma unroll
  for (int j = 1; j < 16; ++j) m = fmaxf(m, lg[j]);
  float s = 0.0f;
  float e[16];
#pragma unroll
  for (int j = 0; j < 16; ++j) {
    e[j] = expf(lg[j] - m);
    s += e[j];
  }
  float inv = 1.0f / s;
  float o0 = 0.0f, o1 = 0.0f;
#pragma unroll
  for (int j = 0; j < 16; ++j) {
    float a = e[j] * inv;
    o0 += a * t0a[j];
    o1 += a * t1a[j];
  }
  *(float2*)(out + g * 128 + 2 * lane) = make_float2(o0, o1);
}

// ---------------------------------------------------------------------------
extern "C" void kernel_launch(void* const* d_in, const int* in_sizes, int n_in,
                              void* d_out, int out_size, void* d_ws,
                              size_t ws_size, hipStream_t stream) {
  const float* x = (const float*)d_in[0];
  const float* pos = (const float*)d_in[1];
  const float* coords = (const float*)d_in[2];
  const float* gamma = (const float*)d_in[3];
  const float* beta = (const float*)d_in[4];
  const float* Wa1 = (const float*)d_in[5];
  const float* ba1 = (const float*)d_in[6];
  const float* Wa2 = (const float*)d_in[7];
  const float* ba2 = (const float*)d_in[8];
  const float* Wf1 = (const float*)d_in[9];
  const float* bf1 = (const float*)d_in[10];
  float* out = (float*)d_out;

  char* ws = (char*)d_ws;
  unsigned short* A = (unsigned short*)ws;                          // 8MB
  unsigned short* SN = (unsigned short*)(ws + (size_t)16 * 1024 * 1024);  // 32MB
  unsigned short* WT = (unsigned short*)(ws + (size_t)80 * 1024 * 1024);  // 128KB
  int* idx = (int*)(ws + (size_t)80 * 1024 * 1024 + 512 * 1024);    // 2MB
  float4* cc4 = (float4*)(ws + (size_t)80 * 1024 * 1024 + 2560 * 1024);  // 512KB

  k_pack<<<128, 256, 0, stream>>>(coords, cc4);
  k_lnpos<<<8192, 256, 0, stream>>>(x, pos, gamma, beta, A);
  k_wcatT<<<256, 256, 0, stream>>>(Wa1, Wf1, WT);
  k_knn3<<<B_ * 256, 256, 0, stream>>>(cc4, idx);
  k_gemm_mfma<<<1024, 256, 0, stream>>>(A, WT, SN);
  k_attn<<<8192, 256, 0, stream>>>(SN, idx, ba1, bf1, Wa2, ba2, out);
}